// Round 10
// baseline (347.478 us; speedup 1.0000x reference)
//
#include <hip/hip_runtime.h>
#include <stddef.h>

// Problem constants (from reference)
#define N_NODES 100000
#define N_EDGES 1600000
#define DIM_IN  48
#define DIM_U   128
#define DIM_OUT 128

// History: R7 CSR+MLP 713; R8 scan 483; R9 prop float4 466; R10 bucket CSR
// 333; R11/R13/R14 mlp experiments regressed; R15 328 (BEST); R16 degsort
// FAILED 344 (divergence not binding -> prop is gather-traffic-bound);
// R17 fusion neutral 328 (launch gaps negligible; mlp_tail absorbs tail free).
// R18 (this round): mlp VALUBusy 49% explained by LDS-issue: layer2 does
// 8x ds_read_b128 (~96cyc) per 128 wave-FMA (~256cyc). Re-tile 8x4 -> 4x8
// (4 nodes x 8 cols/thread): LDS reads per FMA halve; k4-batched b128 x
// loads in layer1. Per-output k-order unchanged -> bitwise-identical.

typedef float nf4 __attribute__((ext_vector_type(4)));

#define B_BKT     196                 // ceil(N_NODES/512)
#define BKT_SHIFT 9
#define NPB       512                 // nodes per bucket
#define AP_WGS    256                 // append/hist workgroups (R15 proven)
#define EDGES_PER_WG ((N_EDGES + AP_WGS - 1) / AP_WGS)   // 6250
#define BKT_CAP   10240               // LDS record staging (mean 8192, +22 sd)

#define MLPB      ((N_NODES + 63) / 64)   // 1563 mlp blocks
#define TAILB     4096                    // tail blocks (grid-strided)

// ---------- stage 1: per-WG per-bucket histogram (no global atomics) ----------
__global__ __launch_bounds__(256) void histcount_kernel(const int* __restrict__ en,
                                                        int* __restrict__ partial) {
    __shared__ int lh[B_BKT];
    int w = blockIdx.x, t = threadIdx.x;
    for (int i = t; i < B_BKT; i += 256) lh[i] = 0;
    __syncthreads();
    int lo = w * EDGES_PER_WG;
    int hi = min(lo + EDGES_PER_WG, N_EDGES);
    for (int i = lo + t; i < hi; i += 256)
        atomicAdd(&lh[((unsigned)en[i]) >> BKT_SHIFT], 1);
    __syncthreads();
    for (int b = t; b < B_BKT; b += 256)
        partial[b * AP_WGS + w] = lh[b];   // bucket-major for colscan
}

// ---------- stage 2: per-bucket exclusive scan over the AP_WGS partials ----------
__global__ __launch_bounds__(256) void colscan_kernel(int* __restrict__ partial,
                                                      int* __restrict__ bcnt) {
    __shared__ int part[256];
    int b = blockIdx.x, t = threadIdx.x;
    int v = partial[b * AP_WGS + t];
    part[t] = v;
    __syncthreads();
    for (int off = 1; off < 256; off <<= 1) {
        int u = (t >= off) ? part[t - off] : 0;
        __syncthreads();
        part[t] += u;
        __syncthreads();
    }
    partial[b * AP_WGS + t] = part[t] - v;  // exclusive over WGs
    if (t == 255) bcnt[b] = part[255];
}

// ---------- stage 3: deterministic chunked append of packed records ----------
// bbase re-derived locally from bcnt (R17: bscan kernel deleted).
__global__ __launch_bounds__(256) void scatter_rb_kernel(const int* __restrict__ sn,
                                                         const int* __restrict__ en,
                                                         const float* __restrict__ dfs,
                                                         const int* __restrict__ partial,
                                                         const int* __restrict__ bcnt,
                                                         int2* __restrict__ rb) {
    __shared__ int lh[B_BKT];
    __shared__ int basec[B_BKT];
    __shared__ int sc[256];
    int w = blockIdx.x, t = threadIdx.x;
    int v = (t < B_BKT) ? bcnt[t] : 0;
    sc[t] = v;
    __syncthreads();
    for (int off = 1; off < 256; off <<= 1) {
        int u = (t >= off) ? sc[t - off] : 0;
        __syncthreads();
        sc[t] += u;
        __syncthreads();
    }
    if (t < B_BKT) {
        lh[t] = 0;
        basec[t] = (sc[t] - v) + partial[t * AP_WGS + w];
    }
    __syncthreads();
    int lo = w * EDGES_PER_WG;
    int hi = min(lo + EDGES_PER_WG, N_EDGES);
    for (int i = lo + t; i < hi; i += 256) {
        int e = en[i];
        int b = ((unsigned)e) >> BKT_SHIFT;
        int r = atomicAdd(&lh[b], 1);           // LDS rank within chunk
        int pos = basec[b] + r;
        unsigned packed = (unsigned)sn[i] | (((unsigned)e & (NPB - 1)) << 17);
        rb[pos] = make_int2((int)packed, __float_as_int(dfs[i]));
    }
}

// ---------- stage 4: per-bucket local CSR build (in-place, L2-resident) ----------
__global__ __launch_bounds__(512) void bucket_fill_kernel(const int2* __restrict__ rb,
                                                          const int* __restrict__ bcnt,
                                                          int* __restrict__ rowptr,
                                                          int2* __restrict__ pe,
                                                          int n_nodes) {
    __shared__ int2 stage[BKT_CAP];   // 80 KB
    __shared__ int ldeg[NPB];
    __shared__ int lscan[NPB];
    __shared__ int sc[512];
    __shared__ int s_lo, s_hi;
    int b = blockIdx.x, t = threadIdx.x;
    int v = (t < B_BKT) ? bcnt[t] : 0;
    sc[t] = v;
    __syncthreads();
    for (int off = 1; off < 512; off <<= 1) {
        int u = (t >= off) ? sc[t - off] : 0;
        __syncthreads();
        sc[t] += u;
        __syncthreads();
    }
    if (t == b) { s_lo = sc[t] - v; s_hi = sc[t]; }
    __syncthreads();
    int lo = s_lo, hi = s_hi;
    int cnt = hi - lo;
    for (int i = t; i < NPB; i += 512) ldeg[i] = 0;
    __syncthreads();
    for (int i = t; i < cnt; i += 512) {
        int2 r = rb[lo + i];
        if (i < BKT_CAP) stage[i] = r;
        atomicAdd(&ldeg[((unsigned)r.x) >> 17], 1);
    }
    __syncthreads();
    int dv = ldeg[t];
    lscan[t] = dv;
    __syncthreads();
    for (int off = 1; off < 512; off <<= 1) {
        int u = (t >= off) ? lscan[t - off] : 0;
        __syncthreads();
        lscan[t] += u;
        __syncthreads();
    }
    int excl = lscan[t] - dv;
    int node = b * NPB + t;
    if (node < n_nodes) rowptr[node] = lo + excl;
    if (b == B_BKT - 1 && t == 0) rowptr[n_nodes] = N_EDGES;
    ldeg[t] = lo + excl;              // reuse as cursor
    __syncthreads();
    for (int i = t; i < cnt; i += 512) {
        int2 r = (i < BKT_CAP) ? stage[i] : rb[lo + i];
        int dl = ((unsigned)r.x) >> 17;
        int pos = atomicAdd(&ldeg[dl], 1);
        pe[pos] = make_int2(r.x & 0x1FFFF, r.y);
    }
}

// ---------------- propagation: per-node gather (no atomics) ----------------
// 12 lanes/node, float4 per lane, 8-edge unroll (R15 proven).
__global__ __launch_bounds__(192) void prop_kernel(const float* __restrict__ yin,
                                                   float* __restrict__ yout,
                                                   const int* __restrict__ rowptr,
                                                   const int2* __restrict__ pe,
                                                   const float* __restrict__ dfn,
                                                   int n_nodes) {
    int n = blockIdx.x * 16 + threadIdx.y;
    if (n >= n_nodes) return;
    int d4 = threadIdx.x * 4;  // 0,4,...,44
    int lo = rowptr[n];
    int hi = rowptr[n + 1];
    float4 acc = make_float4(0.f, 0.f, 0.f, 0.f);
    int e = lo;
    for (; e + 8 <= hi; e += 8) {
        int2 e0 = pe[e],     e1 = pe[e + 1], e2 = pe[e + 2], e3 = pe[e + 3];
        int2 e4 = pe[e + 4], e5 = pe[e + 5], e6 = pe[e + 6], e7 = pe[e + 7];
        float4 v0 = *(const float4*)&yin[(size_t)e0.x * DIM_IN + d4];
        float4 v1 = *(const float4*)&yin[(size_t)e1.x * DIM_IN + d4];
        float4 v2 = *(const float4*)&yin[(size_t)e2.x * DIM_IN + d4];
        float4 v3 = *(const float4*)&yin[(size_t)e3.x * DIM_IN + d4];
        float4 v4 = *(const float4*)&yin[(size_t)e4.x * DIM_IN + d4];
        float4 v5 = *(const float4*)&yin[(size_t)e5.x * DIM_IN + d4];
        float4 v6 = *(const float4*)&yin[(size_t)e6.x * DIM_IN + d4];
        float4 v7 = *(const float4*)&yin[(size_t)e7.x * DIM_IN + d4];
        float w0 = __int_as_float(e0.y), w1 = __int_as_float(e1.y);
        float w2 = __int_as_float(e2.y), w3 = __int_as_float(e3.y);
        float w4 = __int_as_float(e4.y), w5 = __int_as_float(e5.y);
        float w6 = __int_as_float(e6.y), w7 = __int_as_float(e7.y);
        acc.x = fmaf(v0.x, w0, acc.x); acc.y = fmaf(v0.y, w0, acc.y);
        acc.z = fmaf(v0.z, w0, acc.z); acc.w = fmaf(v0.w, w0, acc.w);
        acc.x = fmaf(v1.x, w1, acc.x); acc.y = fmaf(v1.y, w1, acc.y);
        acc.z = fmaf(v1.z, w1, acc.z); acc.w = fmaf(v1.w, w1, acc.w);
        acc.x = fmaf(v2.x, w2, acc.x); acc.y = fmaf(v2.y, w2, acc.y);
        acc.z = fmaf(v2.z, w2, acc.z); acc.w = fmaf(v2.w, w2, acc.w);
        acc.x = fmaf(v3.x, w3, acc.x); acc.y = fmaf(v3.y, w3, acc.y);
        acc.z = fmaf(v3.z, w3, acc.z); acc.w = fmaf(v3.w, w3, acc.w);
        acc.x = fmaf(v4.x, w4, acc.x); acc.y = fmaf(v4.y, w4, acc.y);
        acc.z = fmaf(v4.z, w4, acc.z); acc.w = fmaf(v4.w, w4, acc.w);
        acc.x = fmaf(v5.x, w5, acc.x); acc.y = fmaf(v5.y, w5, acc.y);
        acc.z = fmaf(v5.z, w5, acc.z); acc.w = fmaf(v5.w, w5, acc.w);
        acc.x = fmaf(v6.x, w6, acc.x); acc.y = fmaf(v6.y, w6, acc.y);
        acc.z = fmaf(v6.z, w6, acc.z); acc.w = fmaf(v6.w, w6, acc.w);
        acc.x = fmaf(v7.x, w7, acc.x); acc.y = fmaf(v7.y, w7, acc.y);
        acc.z = fmaf(v7.z, w7, acc.z); acc.w = fmaf(v7.w, w7, acc.w);
    }
    for (; e + 4 <= hi; e += 4) {
        int2 e0 = pe[e], e1 = pe[e + 1], e2 = pe[e + 2], e3 = pe[e + 3];
        float4 v0 = *(const float4*)&yin[(size_t)e0.x * DIM_IN + d4];
        float4 v1 = *(const float4*)&yin[(size_t)e1.x * DIM_IN + d4];
        float4 v2 = *(const float4*)&yin[(size_t)e2.x * DIM_IN + d4];
        float4 v3 = *(const float4*)&yin[(size_t)e3.x * DIM_IN + d4];
        float w0 = __int_as_float(e0.y), w1 = __int_as_float(e1.y);
        float w2 = __int_as_float(e2.y), w3 = __int_as_float(e3.y);
        acc.x = fmaf(v0.x, w0, acc.x); acc.y = fmaf(v0.y, w0, acc.y);
        acc.z = fmaf(v0.z, w0, acc.z); acc.w = fmaf(v0.w, w0, acc.w);
        acc.x = fmaf(v1.x, w1, acc.x); acc.y = fmaf(v1.y, w1, acc.y);
        acc.z = fmaf(v1.z, w1, acc.z); acc.w = fmaf(v1.w, w1, acc.w);
        acc.x = fmaf(v2.x, w2, acc.x); acc.y = fmaf(v2.y, w2, acc.y);
        acc.z = fmaf(v2.z, w2, acc.z); acc.w = fmaf(v2.w, w2, acc.w);
        acc.x = fmaf(v3.x, w3, acc.x); acc.y = fmaf(v3.y, w3, acc.y);
        acc.z = fmaf(v3.z, w3, acc.z); acc.w = fmaf(v3.w, w3, acc.w);
    }
    for (; e < hi; ++e) {
        int2 ee = pe[e];
        float w = __int_as_float(ee.y);
        float4 v = *(const float4*)&yin[(size_t)ee.x * DIM_IN + d4];
        acc.x = fmaf(v.x, w, acc.x); acc.y = fmaf(v.y, w, acc.y);
        acc.z = fmaf(v.z, w, acc.z); acc.w = fmaf(v.w, w, acc.w);
    }
    if (dfn) {
        float s = dfn[n];
        acc.x *= s; acc.y *= s; acc.z *= s; acc.w *= s;
    }
    *(float4*)&yout[(size_t)n * DIM_IN + d4] = acc;
}

// ---------------- fallback: atomic scatter (R6 proven path) ----------------
__global__ __launch_bounds__(192) void scatter1_kernel(
    const float* __restrict__ yin, float* __restrict__ yout,
    const int* __restrict__ sn, const int* __restrict__ en,
    const float* __restrict__ dfs, int E)
{
    int e = blockIdx.x * 4 + threadIdx.y;
    if (e >= E) return;
    int d = threadIdx.x;
    int s = sn[e], dn = en[e];
    float v = yin[(size_t)s * DIM_IN + d] * dfs[e];
    atomicAdd(&yout[(size_t)dn * DIM_IN + d], v);
}
__global__ __launch_bounds__(192) void scatter2_kernel(
    const float* __restrict__ yin, float* __restrict__ yout,
    const int* __restrict__ sn, const int* __restrict__ en,
    const float* __restrict__ dfs, const float* __restrict__ df, int E)
{
    int e = blockIdx.x * 4 + threadIdx.y;
    if (e >= E) return;
    int d = threadIdx.x;
    int s = sn[e], dn = en[e];
    float w = dfs[e] * df[s];
    float v = yin[(size_t)s * DIM_IN + d] * w;
    atomicAdd(&yout[(size_t)dn * DIM_IN + d], v);
}
__global__ __launch_bounds__(256) void zerof_kernel(float* __restrict__ p, int n) {
    int i = blockIdx.x * 256 + threadIdx.x;
    if (i < n) p[i] = 0.0f;
}

// ---------------- fused MLP (R18: 4 nodes x 8 cols/thread) + tail ------------
// Blocks [0, MLPB): mlp. Blocks [MLPB, MLPB+TAILB): grid-strided tail.
// Re-tile halves LDS reads per FMA (layer2: 4x b128 per 128 FMAs vs 8x).
// Per-output accumulation stays k-ascending -> bitwise-identical results.
__global__ __launch_bounds__(256) void mlp_tail_kernel(
    const float* __restrict__ y2, const float* __restrict__ df,
    const float* __restrict__ W1, const float* __restrict__ b1,
    const float* __restrict__ W2, const float* __restrict__ b2,
    const int* __restrict__ sn, const int* __restrict__ en,
    const float* __restrict__ dfs,
    float* __restrict__ out, int n_nodes)
{
    __shared__ float xs[64 * DIM_IN];  // 12.3 KB
    __shared__ float hs[64 * DIM_U];   // 32.8 KB
    int t = threadIdx.x;

    if (blockIdx.x >= MLPB) {
        // ---- tail part ----
        const int E = N_EDGES, Nn = N_NODES;
        int total = 3 * E + Nn;
        for (int i = (blockIdx.x - MLPB) * 256 + t; i < total; i += TAILB * 256) {
            float v;
            if (i < E) v = (float)sn[i];
            else if (i < 2 * E) v = (float)en[i - E];
            else if (i < 3 * E) v = dfs[i - 2 * E];
            else v = df[i - 3 * E];
            __builtin_nontemporal_store(v, &out[(size_t)Nn * DIM_OUT + (size_t)i]);
        }
        return;
    }

    // ---- mlp part ----
    int node0 = blockIdx.x * 64;

    for (int i4 = t; i4 < 64 * DIM_IN / 4; i4 += 256) {
        int n = node0 + i4 / (DIM_IN / 4);
        float4 v = make_float4(0.f, 0.f, 0.f, 0.f);
        if (n < n_nodes) {
            v = *(const float4*)&y2[(size_t)node0 * DIM_IN + (size_t)i4 * 4];
            float s = df[n];
            v.x *= s; v.y *= s; v.z *= s; v.w *= s;
        }
        *(float4*)&xs[i4 * 4] = v;
    }
    __syncthreads();

    int cg = t & 15;   // cols 8*cg..8*cg+7
    int ng = t >> 4;   // node-group 0..15 -> local nodes 4*ng..4*ng+3
    int nb = ng * 4;

    // ---- layer 1: h = relu(x @ W1 + b1), acc[4 nodes][8 cols] ----
    float acc[4][8];
    #pragma unroll
    for (int m = 0; m < 4; ++m)
        #pragma unroll
        for (int c = 0; c < 8; ++c) acc[m][c] = 0.f;
    const float* xbase = &xs[nb * DIM_IN];
    for (int k4 = 0; k4 < DIM_IN; k4 += 4) {
        float4 xv[4];
        #pragma unroll
        for (int m = 0; m < 4; ++m)
            xv[m] = *(const float4*)&xbase[m * DIM_IN + k4];
        #pragma unroll
        for (int kk = 0; kk < 4; ++kk) {
            float4 wa = *(const float4*)&W1[(k4 + kk) * DIM_U + cg * 8];
            float4 wb = *(const float4*)&W1[(k4 + kk) * DIM_U + cg * 8 + 4];
            #pragma unroll
            for (int m = 0; m < 4; ++m) {
                float xk = (kk == 0) ? xv[m].x : (kk == 1) ? xv[m].y
                         : (kk == 2) ? xv[m].z : xv[m].w;
                acc[m][0] = fmaf(xk, wa.x, acc[m][0]);
                acc[m][1] = fmaf(xk, wa.y, acc[m][1]);
                acc[m][2] = fmaf(xk, wa.z, acc[m][2]);
                acc[m][3] = fmaf(xk, wa.w, acc[m][3]);
                acc[m][4] = fmaf(xk, wb.x, acc[m][4]);
                acc[m][5] = fmaf(xk, wb.y, acc[m][5]);
                acc[m][6] = fmaf(xk, wb.z, acc[m][6]);
                acc[m][7] = fmaf(xk, wb.w, acc[m][7]);
            }
        }
    }
    {
        float4 ba = *(const float4*)&b1[cg * 8];
        float4 bb = *(const float4*)&b1[cg * 8 + 4];
        #pragma unroll
        for (int m = 0; m < 4; ++m) {
            float4 h0, h1;
            h0.x = fmaxf(acc[m][0] + ba.x, 0.f);
            h0.y = fmaxf(acc[m][1] + ba.y, 0.f);
            h0.z = fmaxf(acc[m][2] + ba.z, 0.f);
            h0.w = fmaxf(acc[m][3] + ba.w, 0.f);
            h1.x = fmaxf(acc[m][4] + bb.x, 0.f);
            h1.y = fmaxf(acc[m][5] + bb.y, 0.f);
            h1.z = fmaxf(acc[m][6] + bb.z, 0.f);
            h1.w = fmaxf(acc[m][7] + bb.w, 0.f);
            *(float4*)&hs[(nb + m) * DIM_U + cg * 8] = h0;
            *(float4*)&hs[(nb + m) * DIM_U + cg * 8 + 4] = h1;
        }
    }
    __syncthreads();

    // ---- layer 2: out = h @ W2 + b2, acc2[4 nodes][8 cols] ----
    float acc2[4][8];
    #pragma unroll
    for (int m = 0; m < 4; ++m)
        #pragma unroll
        for (int c = 0; c < 8; ++c) acc2[m][c] = 0.f;
    const float* hbase = &hs[nb * DIM_U];
    for (int k4 = 0; k4 < DIM_U; k4 += 4) {
        float4 hv[4];
        #pragma unroll
        for (int m = 0; m < 4; ++m)
            hv[m] = *(const float4*)&hbase[m * DIM_U + k4];
        #pragma unroll
        for (int kk = 0; kk < 4; ++kk) {
            float4 wa = *(const float4*)&W2[(k4 + kk) * DIM_OUT + cg * 8];
            float4 wb = *(const float4*)&W2[(k4 + kk) * DIM_OUT + cg * 8 + 4];
            #pragma unroll
            for (int m = 0; m < 4; ++m) {
                float hk = (kk == 0) ? hv[m].x : (kk == 1) ? hv[m].y
                         : (kk == 2) ? hv[m].z : hv[m].w;
                acc2[m][0] = fmaf(hk, wa.x, acc2[m][0]);
                acc2[m][1] = fmaf(hk, wa.y, acc2[m][1]);
                acc2[m][2] = fmaf(hk, wa.z, acc2[m][2]);
                acc2[m][3] = fmaf(hk, wa.w, acc2[m][3]);
                acc2[m][4] = fmaf(hk, wb.x, acc2[m][4]);
                acc2[m][5] = fmaf(hk, wb.y, acc2[m][5]);
                acc2[m][6] = fmaf(hk, wb.z, acc2[m][6]);
                acc2[m][7] = fmaf(hk, wb.w, acc2[m][7]);
            }
        }
    }
    {
        float4 ba = *(const float4*)&b2[cg * 8];
        float4 bb = *(const float4*)&b2[cg * 8 + 4];
        #pragma unroll
        for (int m = 0; m < 4; ++m) {
            int n = node0 + nb + m;
            if (n < n_nodes) {
                float4 o0, o1;
                o0.x = acc2[m][0] + ba.x;
                o0.y = acc2[m][1] + ba.y;
                o0.z = acc2[m][2] + ba.z;
                o0.w = acc2[m][3] + ba.w;
                o1.x = acc2[m][4] + bb.x;
                o1.y = acc2[m][5] + bb.y;
                o1.z = acc2[m][6] + bb.z;
                o1.w = acc2[m][7] + bb.w;
                *(float4*)&out[(size_t)n * DIM_OUT + cg * 8] = o0;
                *(float4*)&out[(size_t)n * DIM_OUT + cg * 8 + 4] = o1;
            }
        }
    }
}

extern "C" void kernel_launch(void* const* d_in, const int* in_sizes, int n_in,
                              void* d_out, int out_size, void* d_ws, size_t ws_size,
                              hipStream_t stream) {
    const float* y   = (const float*)d_in[0];
    const int* start = (const int*)d_in[1];
    const int* endn  = (const int*)d_in[2];
    const float* dfs = (const float*)d_in[3];
    const float* df  = (const float*)d_in[4];
    const float* W1  = (const float*)d_in[5];
    const float* b1  = (const float*)d_in[6];
    const float* W2  = (const float*)d_in[7];
    const float* b2  = (const float*)d_in[8];
    float* out = (float*)d_out;

    const int N = N_NODES, E = N_EDGES;
    const size_t Y_ELEMS = (size_t)N * DIM_IN;  // 4.8M floats

    // Workspace carve (CSR path): ~52 MB (rb aliases pe -> in-place CSR build)
    char* ws = (char*)d_ws;
    size_t off = 0;
    auto carve = [&](size_t bytes) -> void* {
        void* p = ws + off;
        off = (off + bytes + 255) & ~(size_t)255;
        return p;
    };
    int*   rowptr  = (int*)carve((size_t)(N + 1) * 4);
    int*   partial = (int*)carve((size_t)B_BKT * AP_WGS * 4);   // 200 KB
    int*   bcnt    = (int*)carve((size_t)B_BKT * 4);
    int2*  pedge   = (int2*)carve((size_t)E * 8);               // rb == pe (in place)
    float* y1      = (float*)carve(Y_ELEMS * 4);
    float* y2      = (float*)carve(Y_ELEMS * 4);
    size_t CSR_NEED = off;                                      // ~52 MB

    if (ws_size >= CSR_NEED) {
        // ---- deterministic bucket-binned CSR build (no contended atomics) ----
        histcount_kernel<<<AP_WGS, 256, 0, stream>>>(endn, partial);
        colscan_kernel<<<B_BKT, 256, 0, stream>>>(partial, bcnt);
        scatter_rb_kernel<<<AP_WGS, 256, 0, stream>>>(start, endn, dfs, partial,
                                                      bcnt, pedge);
        bucket_fill_kernel<<<B_BKT, 512, 0, stream>>>(pedge, bcnt, rowptr,
                                                      pedge, N);
        // Pass 1: y1 = gather-sum(y * w) * df[n]   (df folded into epilogue)
        prop_kernel<<<(N + 15) / 16, dim3(12, 16), 0, stream>>>(y, y1, rowptr, pedge,
                                                                df, N);
        // Pass 2: y2 = gather-sum(y1 * w)          (mlp applies final df)
        prop_kernel<<<(N + 15) / 16, dim3(12, 16), 0, stream>>>(y1, y2, rowptr, pedge,
                                                                nullptr, N);
    } else {
        // ---- fallback: R6 proven atomic-scatter path (needs 38.4 MB) ----
        float* fy1 = (float*)d_ws;
        float* fy2 = fy1 + Y_ELEMS;
        y2 = fy2;
        int zn = (int)(2 * Y_ELEMS);
        zerof_kernel<<<(zn + 255) / 256, 256, 0, stream>>>(fy1, zn);
        scatter1_kernel<<<(E + 3) / 4, dim3(48, 4), 0, stream>>>(y, fy1, start, endn,
                                                                 dfs, E);
        scatter2_kernel<<<(E + 3) / 4, dim3(48, 4), 0, stream>>>(fy1, fy2, start, endn,
                                                                 dfs, df, E);
    }

    // Fused: MLP on x = y2*df -> out[0..N*128)  +  tail passthrough
    mlp_tail_kernel<<<MLPB + TAILB, 256, 0, stream>>>(
        y2, df, W1, b1, W2, b2, start, endn, dfs, out, N);
}

// Round 11
// 341.086 us; speedup vs baseline: 1.0187x; 1.0187x over previous
//
#include <hip/hip_runtime.h>
#include <stddef.h>

// Problem constants (from reference)
#define N_NODES 100000
#define N_EDGES 1600000
#define DIM_IN  48
#define DIM_U   128
#define DIM_OUT 128

// History: R10 bucket CSR 333; R15 prop 8-edge unroll 328 (BEST); R16 degsort
// FAILED (divergence not binding); R17 fusion neutral 328; R18 4x8 re-tile
// FAILED 347 — SQ_LDS_BANK_CONFLICT 0->4.8M (hs writes at cg*8 = 16-way
// write conflict; reads were broadcast/free all along). LESSON: keep R10's
// cg*4 write layout untouched. R19 (this round):
//  (1) mlp: batch xs/hs READS as b128 per k4 (loads only; write layout and
//      per-output k-order unchanged -> bitwise identical).
//  (2) prop: NT loads for single-use pe stream (stop evicting gather set
//      from L2); NT store for pass-2 y2 (read only sequentially by mlp).

typedef float nf4 __attribute__((ext_vector_type(4)));
typedef int   ni2 __attribute__((ext_vector_type(2)));

#define B_BKT     196                 // ceil(N_NODES/512)
#define BKT_SHIFT 9
#define NPB       512                 // nodes per bucket
#define AP_WGS    256                 // append/hist workgroups (R15 proven)
#define EDGES_PER_WG ((N_EDGES + AP_WGS - 1) / AP_WGS)   // 6250
#define BKT_CAP   10240               // LDS record staging (mean 8192, +22 sd)

#define MLPB      ((N_NODES + 63) / 64)   // 1563 mlp blocks
#define TAILB     4096                    // tail blocks (grid-strided)

// ---------- stage 1: per-WG per-bucket histogram (no global atomics) ----------
__global__ __launch_bounds__(256) void histcount_kernel(const int* __restrict__ en,
                                                        int* __restrict__ partial) {
    __shared__ int lh[B_BKT];
    int w = blockIdx.x, t = threadIdx.x;
    for (int i = t; i < B_BKT; i += 256) lh[i] = 0;
    __syncthreads();
    int lo = w * EDGES_PER_WG;
    int hi = min(lo + EDGES_PER_WG, N_EDGES);
    for (int i = lo + t; i < hi; i += 256)
        atomicAdd(&lh[((unsigned)en[i]) >> BKT_SHIFT], 1);
    __syncthreads();
    for (int b = t; b < B_BKT; b += 256)
        partial[b * AP_WGS + w] = lh[b];   // bucket-major for colscan
}

// ---------- stage 2: per-bucket exclusive scan over the AP_WGS partials ----------
__global__ __launch_bounds__(256) void colscan_kernel(int* __restrict__ partial,
                                                      int* __restrict__ bcnt) {
    __shared__ int part[256];
    int b = blockIdx.x, t = threadIdx.x;
    int v = partial[b * AP_WGS + t];
    part[t] = v;
    __syncthreads();
    for (int off = 1; off < 256; off <<= 1) {
        int u = (t >= off) ? part[t - off] : 0;
        __syncthreads();
        part[t] += u;
        __syncthreads();
    }
    partial[b * AP_WGS + t] = part[t] - v;  // exclusive over WGs
    if (t == 255) bcnt[b] = part[255];
}

// ---------- stage 3: deterministic chunked append of packed records ----------
// bbase re-derived locally from bcnt (R17: bscan kernel deleted).
__global__ __launch_bounds__(256) void scatter_rb_kernel(const int* __restrict__ sn,
                                                         const int* __restrict__ en,
                                                         const float* __restrict__ dfs,
                                                         const int* __restrict__ partial,
                                                         const int* __restrict__ bcnt,
                                                         int2* __restrict__ rb) {
    __shared__ int lh[B_BKT];
    __shared__ int basec[B_BKT];
    __shared__ int sc[256];
    int w = blockIdx.x, t = threadIdx.x;
    int v = (t < B_BKT) ? bcnt[t] : 0;
    sc[t] = v;
    __syncthreads();
    for (int off = 1; off < 256; off <<= 1) {
        int u = (t >= off) ? sc[t - off] : 0;
        __syncthreads();
        sc[t] += u;
        __syncthreads();
    }
    if (t < B_BKT) {
        lh[t] = 0;
        basec[t] = (sc[t] - v) + partial[t * AP_WGS + w];
    }
    __syncthreads();
    int lo = w * EDGES_PER_WG;
    int hi = min(lo + EDGES_PER_WG, N_EDGES);
    for (int i = lo + t; i < hi; i += 256) {
        int e = en[i];
        int b = ((unsigned)e) >> BKT_SHIFT;
        int r = atomicAdd(&lh[b], 1);           // LDS rank within chunk
        int pos = basec[b] + r;
        unsigned packed = (unsigned)sn[i] | (((unsigned)e & (NPB - 1)) << 17);
        rb[pos] = make_int2((int)packed, __float_as_int(dfs[i]));
    }
}

// ---------- stage 4: per-bucket local CSR build (in-place, L2-resident) ----------
__global__ __launch_bounds__(512) void bucket_fill_kernel(const int2* __restrict__ rb,
                                                          const int* __restrict__ bcnt,
                                                          int* __restrict__ rowptr,
                                                          int2* __restrict__ pe,
                                                          int n_nodes) {
    __shared__ int2 stage[BKT_CAP];   // 80 KB
    __shared__ int ldeg[NPB];
    __shared__ int lscan[NPB];
    __shared__ int sc[512];
    __shared__ int s_lo, s_hi;
    int b = blockIdx.x, t = threadIdx.x;
    int v = (t < B_BKT) ? bcnt[t] : 0;
    sc[t] = v;
    __syncthreads();
    for (int off = 1; off < 512; off <<= 1) {
        int u = (t >= off) ? sc[t - off] : 0;
        __syncthreads();
        sc[t] += u;
        __syncthreads();
    }
    if (t == b) { s_lo = sc[t] - v; s_hi = sc[t]; }
    __syncthreads();
    int lo = s_lo, hi = s_hi;
    int cnt = hi - lo;
    for (int i = t; i < NPB; i += 512) ldeg[i] = 0;
    __syncthreads();
    for (int i = t; i < cnt; i += 512) {
        int2 r = rb[lo + i];
        if (i < BKT_CAP) stage[i] = r;
        atomicAdd(&ldeg[((unsigned)r.x) >> 17], 1);
    }
    __syncthreads();
    int dv = ldeg[t];
    lscan[t] = dv;
    __syncthreads();
    for (int off = 1; off < 512; off <<= 1) {
        int u = (t >= off) ? lscan[t - off] : 0;
        __syncthreads();
        lscan[t] += u;
        __syncthreads();
    }
    int excl = lscan[t] - dv;
    int node = b * NPB + t;
    if (node < n_nodes) rowptr[node] = lo + excl;
    if (b == B_BKT - 1 && t == 0) rowptr[n_nodes] = N_EDGES;
    ldeg[t] = lo + excl;              // reuse as cursor
    __syncthreads();
    for (int i = t; i < cnt; i += 512) {
        int2 r = (i < BKT_CAP) ? stage[i] : rb[lo + i];
        int dl = ((unsigned)r.x) >> 17;
        int pos = atomicAdd(&ldeg[dl], 1);
        pe[pos] = make_int2(r.x & 0x1FFFF, r.y);
    }
}

// ---------------- propagation: per-node gather (no atomics) ----------------
// 12 lanes/node, float4 per lane, 8-edge unroll (R15 proven).
// R19: pe loads NT (single-use stream); optional NT yout store (pass 2).
__global__ __launch_bounds__(192) void prop_kernel(const float* __restrict__ yin,
                                                   float* __restrict__ yout,
                                                   const int* __restrict__ rowptr,
                                                   const int2* __restrict__ pe,
                                                   const float* __restrict__ dfn,
                                                   int nt_out,
                                                   int n_nodes) {
    int n = blockIdx.x * 16 + threadIdx.y;
    if (n >= n_nodes) return;
    int d4 = threadIdx.x * 4;  // 0,4,...,44
    int lo = rowptr[n];
    int hi = rowptr[n + 1];
    float4 acc = make_float4(0.f, 0.f, 0.f, 0.f);
    int e = lo;
    for (; e + 8 <= hi; e += 8) {
        ni2 e0 = __builtin_nontemporal_load((const ni2*)&pe[e]);
        ni2 e1 = __builtin_nontemporal_load((const ni2*)&pe[e + 1]);
        ni2 e2 = __builtin_nontemporal_load((const ni2*)&pe[e + 2]);
        ni2 e3 = __builtin_nontemporal_load((const ni2*)&pe[e + 3]);
        ni2 e4 = __builtin_nontemporal_load((const ni2*)&pe[e + 4]);
        ni2 e5 = __builtin_nontemporal_load((const ni2*)&pe[e + 5]);
        ni2 e6 = __builtin_nontemporal_load((const ni2*)&pe[e + 6]);
        ni2 e7 = __builtin_nontemporal_load((const ni2*)&pe[e + 7]);
        float4 v0 = *(const float4*)&yin[(size_t)e0.x * DIM_IN + d4];
        float4 v1 = *(const float4*)&yin[(size_t)e1.x * DIM_IN + d4];
        float4 v2 = *(const float4*)&yin[(size_t)e2.x * DIM_IN + d4];
        float4 v3 = *(const float4*)&yin[(size_t)e3.x * DIM_IN + d4];
        float4 v4 = *(const float4*)&yin[(size_t)e4.x * DIM_IN + d4];
        float4 v5 = *(const float4*)&yin[(size_t)e5.x * DIM_IN + d4];
        float4 v6 = *(const float4*)&yin[(size_t)e6.x * DIM_IN + d4];
        float4 v7 = *(const float4*)&yin[(size_t)e7.x * DIM_IN + d4];
        float w0 = __int_as_float(e0.y), w1 = __int_as_float(e1.y);
        float w2 = __int_as_float(e2.y), w3 = __int_as_float(e3.y);
        float w4 = __int_as_float(e4.y), w5 = __int_as_float(e5.y);
        float w6 = __int_as_float(e6.y), w7 = __int_as_float(e7.y);
        acc.x = fmaf(v0.x, w0, acc.x); acc.y = fmaf(v0.y, w0, acc.y);
        acc.z = fmaf(v0.z, w0, acc.z); acc.w = fmaf(v0.w, w0, acc.w);
        acc.x = fmaf(v1.x, w1, acc.x); acc.y = fmaf(v1.y, w1, acc.y);
        acc.z = fmaf(v1.z, w1, acc.z); acc.w = fmaf(v1.w, w1, acc.w);
        acc.x = fmaf(v2.x, w2, acc.x); acc.y = fmaf(v2.y, w2, acc.y);
        acc.z = fmaf(v2.z, w2, acc.z); acc.w = fmaf(v2.w, w2, acc.w);
        acc.x = fmaf(v3.x, w3, acc.x); acc.y = fmaf(v3.y, w3, acc.y);
        acc.z = fmaf(v3.z, w3, acc.z); acc.w = fmaf(v3.w, w3, acc.w);
        acc.x = fmaf(v4.x, w4, acc.x); acc.y = fmaf(v4.y, w4, acc.y);
        acc.z = fmaf(v4.z, w4, acc.z); acc.w = fmaf(v4.w, w4, acc.w);
        acc.x = fmaf(v5.x, w5, acc.x); acc.y = fmaf(v5.y, w5, acc.y);
        acc.z = fmaf(v5.z, w5, acc.z); acc.w = fmaf(v5.w, w5, acc.w);
        acc.x = fmaf(v6.x, w6, acc.x); acc.y = fmaf(v6.y, w6, acc.y);
        acc.z = fmaf(v6.z, w6, acc.z); acc.w = fmaf(v6.w, w6, acc.w);
        acc.x = fmaf(v7.x, w7, acc.x); acc.y = fmaf(v7.y, w7, acc.y);
        acc.z = fmaf(v7.z, w7, acc.z); acc.w = fmaf(v7.w, w7, acc.w);
    }
    for (; e + 4 <= hi; e += 4) {
        ni2 e0 = __builtin_nontemporal_load((const ni2*)&pe[e]);
        ni2 e1 = __builtin_nontemporal_load((const ni2*)&pe[e + 1]);
        ni2 e2 = __builtin_nontemporal_load((const ni2*)&pe[e + 2]);
        ni2 e3 = __builtin_nontemporal_load((const ni2*)&pe[e + 3]);
        float4 v0 = *(const float4*)&yin[(size_t)e0.x * DIM_IN + d4];
        float4 v1 = *(const float4*)&yin[(size_t)e1.x * DIM_IN + d4];
        float4 v2 = *(const float4*)&yin[(size_t)e2.x * DIM_IN + d4];
        float4 v3 = *(const float4*)&yin[(size_t)e3.x * DIM_IN + d4];
        float w0 = __int_as_float(e0.y), w1 = __int_as_float(e1.y);
        float w2 = __int_as_float(e2.y), w3 = __int_as_float(e3.y);
        acc.x = fmaf(v0.x, w0, acc.x); acc.y = fmaf(v0.y, w0, acc.y);
        acc.z = fmaf(v0.z, w0, acc.z); acc.w = fmaf(v0.w, w0, acc.w);
        acc.x = fmaf(v1.x, w1, acc.x); acc.y = fmaf(v1.y, w1, acc.y);
        acc.z = fmaf(v1.z, w1, acc.z); acc.w = fmaf(v1.w, w1, acc.w);
        acc.x = fmaf(v2.x, w2, acc.x); acc.y = fmaf(v2.y, w2, acc.y);
        acc.z = fmaf(v2.z, w2, acc.z); acc.w = fmaf(v2.w, w2, acc.w);
        acc.x = fmaf(v3.x, w3, acc.x); acc.y = fmaf(v3.y, w3, acc.y);
        acc.z = fmaf(v3.z, w3, acc.z); acc.w = fmaf(v3.w, w3, acc.w);
    }
    for (; e < hi; ++e) {
        ni2 ee = __builtin_nontemporal_load((const ni2*)&pe[e]);
        float w = __int_as_float(ee.y);
        float4 v = *(const float4*)&yin[(size_t)ee.x * DIM_IN + d4];
        acc.x = fmaf(v.x, w, acc.x); acc.y = fmaf(v.y, w, acc.y);
        acc.z = fmaf(v.z, w, acc.z); acc.w = fmaf(v.w, w, acc.w);
    }
    if (dfn) {
        float s = dfn[n];
        acc.x *= s; acc.y *= s; acc.z *= s; acc.w *= s;
    }
    if (nt_out) {
        nf4 o; o.x = acc.x; o.y = acc.y; o.z = acc.z; o.w = acc.w;
        __builtin_nontemporal_store(o, (nf4*)&yout[(size_t)n * DIM_IN + d4]);
    } else {
        *(float4*)&yout[(size_t)n * DIM_IN + d4] = acc;
    }
}

// ---------------- fallback: atomic scatter (R6 proven path) ----------------
__global__ __launch_bounds__(192) void scatter1_kernel(
    const float* __restrict__ yin, float* __restrict__ yout,
    const int* __restrict__ sn, const int* __restrict__ en,
    const float* __restrict__ dfs, int E)
{
    int e = blockIdx.x * 4 + threadIdx.y;
    if (e >= E) return;
    int d = threadIdx.x;
    int s = sn[e], dn = en[e];
    float v = yin[(size_t)s * DIM_IN + d] * dfs[e];
    atomicAdd(&yout[(size_t)dn * DIM_IN + d], v);
}
__global__ __launch_bounds__(192) void scatter2_kernel(
    const float* __restrict__ yin, float* __restrict__ yout,
    const int* __restrict__ sn, const int* __restrict__ en,
    const float* __restrict__ dfs, const float* __restrict__ df, int E)
{
    int e = blockIdx.x * 4 + threadIdx.y;
    if (e >= E) return;
    int d = threadIdx.x;
    int s = sn[e], dn = en[e];
    float w = dfs[e] * df[s];
    float v = yin[(size_t)s * DIM_IN + d] * w;
    atomicAdd(&yout[(size_t)dn * DIM_IN + d], v);
}
__global__ __launch_bounds__(256) void zerof_kernel(float* __restrict__ p, int n) {
    int i = blockIdx.x * 256 + threadIdx.x;
    if (i < n) p[i] = 0.0f;
}

// ---------------- fused MLP (R10 tile + R19 b128 reads) + tail ----------------
// Blocks [0, MLPB): mlp. Blocks [MLPB, MLPB+TAILB): grid-strided tail.
// 8x4 tile and cg*4 write layout EXACTLY as R10 (0 bank conflicts proven).
// Only change: xs/hs reads batched as b128 per k4 (broadcast, conflict-free);
// per-output k-order unchanged -> bitwise-identical.
__global__ __launch_bounds__(256) void mlp_tail_kernel(
    const float* __restrict__ y2, const float* __restrict__ df,
    const float* __restrict__ W1, const float* __restrict__ b1,
    const float* __restrict__ W2, const float* __restrict__ b2,
    const int* __restrict__ sn, const int* __restrict__ en,
    const float* __restrict__ dfs,
    float* __restrict__ out, int n_nodes)
{
    __shared__ float xs[64 * DIM_IN];  // 12.3 KB
    __shared__ float hs[64 * DIM_U];   // 32.8 KB
    int t = threadIdx.x;

    if (blockIdx.x >= MLPB) {
        // ---- tail part ----
        const int E = N_EDGES, Nn = N_NODES;
        int total = 3 * E + Nn;
        for (int i = (blockIdx.x - MLPB) * 256 + t; i < total; i += TAILB * 256) {
            float v;
            if (i < E) v = (float)sn[i];
            else if (i < 2 * E) v = (float)en[i - E];
            else if (i < 3 * E) v = dfs[i - 2 * E];
            else v = df[i - 3 * E];
            __builtin_nontemporal_store(v, &out[(size_t)Nn * DIM_OUT + (size_t)i]);
        }
        return;
    }

    // ---- mlp part ----
    int node0 = blockIdx.x * 64;

    for (int i4 = t; i4 < 64 * DIM_IN / 4; i4 += 256) {
        int n = node0 + i4 / (DIM_IN / 4);
        float4 v = make_float4(0.f, 0.f, 0.f, 0.f);
        if (n < n_nodes) {
            v = *(const float4*)&y2[(size_t)node0 * DIM_IN + (size_t)i4 * 4];
            float s = df[n];
            v.x *= s; v.y *= s; v.z *= s; v.w *= s;
        }
        *(float4*)&xs[i4 * 4] = v;
    }
    __syncthreads();

    int cg = t & 31;   // cols 4*cg..4*cg+3
    int ng = t >> 5;   // nodes 8*ng..8*ng+7

    // ---- layer 1 ----
    float acc[8][4];
    #pragma unroll
    for (int m = 0; m < 8; ++m)
        #pragma unroll
        for (int c = 0; c < 4; ++c) acc[m][c] = 0.f;
    const float* xbase = &xs[ng * 8 * DIM_IN];
    for (int k4 = 0; k4 < DIM_IN; k4 += 4) {
        float4 xv[8];
        #pragma unroll
        for (int m = 0; m < 8; ++m)
            xv[m] = *(const float4*)&xbase[m * DIM_IN + k4];
        #pragma unroll
        for (int kk = 0; kk < 4; ++kk) {
            float4 wv = *(const float4*)&W1[(k4 + kk) * DIM_U + cg * 4];
            #pragma unroll
            for (int m = 0; m < 8; ++m) {
                float xk = (kk == 0) ? xv[m].x : (kk == 1) ? xv[m].y
                         : (kk == 2) ? xv[m].z : xv[m].w;
                acc[m][0] = fmaf(xk, wv.x, acc[m][0]);
                acc[m][1] = fmaf(xk, wv.y, acc[m][1]);
                acc[m][2] = fmaf(xk, wv.z, acc[m][2]);
                acc[m][3] = fmaf(xk, wv.w, acc[m][3]);
            }
        }
    }
    {
        float4 bb = *(const float4*)&b1[cg * 4];
        #pragma unroll
        for (int m = 0; m < 8; ++m) {
            float4 h;
            h.x = fmaxf(acc[m][0] + bb.x, 0.f);
            h.y = fmaxf(acc[m][1] + bb.y, 0.f);
            h.z = fmaxf(acc[m][2] + bb.z, 0.f);
            h.w = fmaxf(acc[m][3] + bb.w, 0.f);
            *(float4*)&hs[(ng * 8 + m) * DIM_U + cg * 4] = h;
        }
    }
    __syncthreads();

    // ---- layer 2 ----
    float acc2[8][4];
    #pragma unroll
    for (int m = 0; m < 8; ++m)
        #pragma unroll
        for (int c = 0; c < 4; ++c) acc2[m][c] = 0.f;
    const float* hbase = &hs[ng * 8 * DIM_U];
    for (int k4 = 0; k4 < DIM_U; k4 += 4) {
        float4 hv[8];
        #pragma unroll
        for (int m = 0; m < 8; ++m)
            hv[m] = *(const float4*)&hbase[m * DIM_U + k4];
        #pragma unroll
        for (int kk = 0; kk < 4; ++kk) {
            float4 wv = *(const float4*)&W2[(k4 + kk) * DIM_OUT + cg * 4];
            #pragma unroll
            for (int m = 0; m < 8; ++m) {
                float hk = (kk == 0) ? hv[m].x : (kk == 1) ? hv[m].y
                         : (kk == 2) ? hv[m].z : hv[m].w;
                acc2[m][0] = fmaf(hk, wv.x, acc2[m][0]);
                acc2[m][1] = fmaf(hk, wv.y, acc2[m][1]);
                acc2[m][2] = fmaf(hk, wv.z, acc2[m][2]);
                acc2[m][3] = fmaf(hk, wv.w, acc2[m][3]);
            }
        }
    }
    {
        float4 bb = *(const float4*)&b2[cg * 4];
        #pragma unroll
        for (int m = 0; m < 8; ++m) {
            int n = node0 + ng * 8 + m;
            if (n < n_nodes) {
                float4 o;
                o.x = acc2[m][0] + bb.x;
                o.y = acc2[m][1] + bb.y;
                o.z = acc2[m][2] + bb.z;
                o.w = acc2[m][3] + bb.w;
                *(float4*)&out[(size_t)n * DIM_OUT + cg * 4] = o;
            }
        }
    }
}

extern "C" void kernel_launch(void* const* d_in, const int* in_sizes, int n_in,
                              void* d_out, int out_size, void* d_ws, size_t ws_size,
                              hipStream_t stream) {
    const float* y   = (const float*)d_in[0];
    const int* start = (const int*)d_in[1];
    const int* endn  = (const int*)d_in[2];
    const float* dfs = (const float*)d_in[3];
    const float* df  = (const float*)d_in[4];
    const float* W1  = (const float*)d_in[5];
    const float* b1  = (const float*)d_in[6];
    const float* W2  = (const float*)d_in[7];
    const float* b2  = (const float*)d_in[8];
    float* out = (float*)d_out;

    const int N = N_NODES, E = N_EDGES;
    const size_t Y_ELEMS = (size_t)N * DIM_IN;  // 4.8M floats

    // Workspace carve (CSR path): ~52 MB (rb aliases pe -> in-place CSR build)
    char* ws = (char*)d_ws;
    size_t off = 0;
    auto carve = [&](size_t bytes) -> void* {
        void* p = ws + off;
        off = (off + bytes + 255) & ~(size_t)255;
        return p;
    };
    int*   rowptr  = (int*)carve((size_t)(N + 1) * 4);
    int*   partial = (int*)carve((size_t)B_BKT * AP_WGS * 4);   // 200 KB
    int*   bcnt    = (int*)carve((size_t)B_BKT * 4);
    int2*  pedge   = (int2*)carve((size_t)E * 8);               // rb == pe (in place)
    float* y1      = (float*)carve(Y_ELEMS * 4);
    float* y2      = (float*)carve(Y_ELEMS * 4);
    size_t CSR_NEED = off;                                      // ~52 MB

    if (ws_size >= CSR_NEED) {
        // ---- deterministic bucket-binned CSR build (no contended atomics) ----
        histcount_kernel<<<AP_WGS, 256, 0, stream>>>(endn, partial);
        colscan_kernel<<<B_BKT, 256, 0, stream>>>(partial, bcnt);
        scatter_rb_kernel<<<AP_WGS, 256, 0, stream>>>(start, endn, dfs, partial,
                                                      bcnt, pedge);
        bucket_fill_kernel<<<B_BKT, 512, 0, stream>>>(pedge, bcnt, rowptr,
                                                      pedge, N);
        // Pass 1: y1 = gather-sum(y * w) * df[n]   (normal store: y1 re-read)
        prop_kernel<<<(N + 15) / 16, dim3(12, 16), 0, stream>>>(y, y1, rowptr, pedge,
                                                                df, 0, N);
        // Pass 2: y2 = gather-sum(y1 * w)  (NT store: y2 only streamed by mlp)
        prop_kernel<<<(N + 15) / 16, dim3(12, 16), 0, stream>>>(y1, y2, rowptr, pedge,
                                                                nullptr, 1, N);
    } else {
        // ---- fallback: R6 proven atomic-scatter path (needs 38.4 MB) ----
        float* fy1 = (float*)d_ws;
        float* fy2 = fy1 + Y_ELEMS;
        y2 = fy2;
        int zn = (int)(2 * Y_ELEMS);
        zerof_kernel<<<(zn + 255) / 256, 256, 0, stream>>>(fy1, zn);
        scatter1_kernel<<<(E + 3) / 4, dim3(48, 4), 0, stream>>>(y, fy1, start, endn,
                                                                 dfs, E);
        scatter2_kernel<<<(E + 3) / 4, dim3(48, 4), 0, stream>>>(fy1, fy2, start, endn,
                                                                 dfs, df, E);
    }

    // Fused: MLP on x = y2*df -> out[0..N*128)  +  tail passthrough
    mlp_tail_kernel<<<MLPB + TAILB, 256, 0, stream>>>(
        y2, df, W1, b1, W2, b2, start, endn, dfs, out, N);
}

// Round 12
// 322.356 us; speedup vs baseline: 1.0779x; 1.0581x over previous
//
#include <hip/hip_runtime.h>
#include <stddef.h>

// Problem constants (from reference)
#define N_NODES 100000
#define N_EDGES 1600000
#define DIM_IN  48
#define DIM_U   128
#define DIM_OUT 128

// History: R7 CSR+MLP 713; R8 scan 483; R9 prop float4 466; R10 bucket CSR
// 333; R11/R13/R14 mlp experiments regressed; R15 328 (BEST); R16 degsort
// FAILED 344; R17 fusion 328 (BEST, fewer dispatches); R18 4x8 re-tile
// FAILED 347 (16-way LDS write conflicts); R19 b128-batch + NT hints FAILED
// 341 (VGPR 68->80, serialized lgkmcnt waits; NT evicted reused pe lines).
// R20: byte-exact revert to R17 — the measured optimum. All counter-driven
// theories for mlp (7 perturbations) and prop (3 theories) tested; each
// falsified. prop ~5+TB/s effective on 327MB/pass (>=80% achievable BW);
// mlp ~75us, VALUBusy ~50%, 0 conflicts; CSR build ~50us deterministic.

typedef float nf4 __attribute__((ext_vector_type(4)));

#define B_BKT     196                 // ceil(N_NODES/512)
#define BKT_SHIFT 9
#define NPB       512                 // nodes per bucket
#define AP_WGS    256                 // append/hist workgroups (R15 proven)
#define EDGES_PER_WG ((N_EDGES + AP_WGS - 1) / AP_WGS)   // 6250
#define BKT_CAP   10240               // LDS record staging (mean 8192, +22 sd)

#define MLPB      ((N_NODES + 63) / 64)   // 1563 mlp blocks
#define TAILB     4096                    // tail blocks (grid-strided)

// ---------- stage 1: per-WG per-bucket histogram (no global atomics) ----------
__global__ __launch_bounds__(256) void histcount_kernel(const int* __restrict__ en,
                                                        int* __restrict__ partial) {
    __shared__ int lh[B_BKT];
    int w = blockIdx.x, t = threadIdx.x;
    for (int i = t; i < B_BKT; i += 256) lh[i] = 0;
    __syncthreads();
    int lo = w * EDGES_PER_WG;
    int hi = min(lo + EDGES_PER_WG, N_EDGES);
    for (int i = lo + t; i < hi; i += 256)
        atomicAdd(&lh[((unsigned)en[i]) >> BKT_SHIFT], 1);
    __syncthreads();
    for (int b = t; b < B_BKT; b += 256)
        partial[b * AP_WGS + w] = lh[b];   // bucket-major for colscan
}

// ---------- stage 2: per-bucket exclusive scan over the AP_WGS partials ----------
// Writes bcnt[b] = bucket total; partial becomes exclusive-over-WGs.
__global__ __launch_bounds__(256) void colscan_kernel(int* __restrict__ partial,
                                                      int* __restrict__ bcnt) {
    __shared__ int part[256];
    int b = blockIdx.x, t = threadIdx.x;
    int v = partial[b * AP_WGS + t];
    part[t] = v;
    __syncthreads();
    for (int off = 1; off < 256; off <<= 1) {
        int u = (t >= off) ? part[t - off] : 0;
        __syncthreads();
        part[t] += u;
        __syncthreads();
    }
    partial[b * AP_WGS + t] = part[t] - v;  // exclusive over WGs
    if (t == 255) bcnt[b] = part[255];
}

// ---------- stage 3: deterministic chunked append of packed records ----------
// bbase re-derived locally from bcnt (R17: bscan kernel deleted).
__global__ __launch_bounds__(256) void scatter_rb_kernel(const int* __restrict__ sn,
                                                         const int* __restrict__ en,
                                                         const float* __restrict__ dfs,
                                                         const int* __restrict__ partial,
                                                         const int* __restrict__ bcnt,
                                                         int2* __restrict__ rb) {
    __shared__ int lh[B_BKT];
    __shared__ int basec[B_BKT];
    __shared__ int sc[256];
    int w = blockIdx.x, t = threadIdx.x;
    // local exclusive scan of bcnt[0..195]
    int v = (t < B_BKT) ? bcnt[t] : 0;
    sc[t] = v;
    __syncthreads();
    for (int off = 1; off < 256; off <<= 1) {
        int u = (t >= off) ? sc[t - off] : 0;
        __syncthreads();
        sc[t] += u;
        __syncthreads();
    }
    if (t < B_BKT) {
        lh[t] = 0;
        basec[t] = (sc[t] - v) + partial[t * AP_WGS + w];
    }
    __syncthreads();
    int lo = w * EDGES_PER_WG;
    int hi = min(lo + EDGES_PER_WG, N_EDGES);
    for (int i = lo + t; i < hi; i += 256) {
        int e = en[i];
        int b = ((unsigned)e) >> BKT_SHIFT;
        int r = atomicAdd(&lh[b], 1);           // LDS rank within chunk
        int pos = basec[b] + r;
        unsigned packed = (unsigned)sn[i] | (((unsigned)e & (NPB - 1)) << 17);
        rb[pos] = make_int2((int)packed, __float_as_int(dfs[i]));
    }
}

// ---------- stage 4: per-bucket local CSR build (in-place, L2-resident) ----------
// bbase re-derived locally from bcnt (R17).
__global__ __launch_bounds__(512) void bucket_fill_kernel(const int2* __restrict__ rb,
                                                          const int* __restrict__ bcnt,
                                                          int* __restrict__ rowptr,
                                                          int2* __restrict__ pe,
                                                          int n_nodes) {
    __shared__ int2 stage[BKT_CAP];   // 80 KB
    __shared__ int ldeg[NPB];
    __shared__ int lscan[NPB];
    __shared__ int sc[512];
    __shared__ int s_lo, s_hi;
    int b = blockIdx.x, t = threadIdx.x;
    // local inclusive scan of bcnt -> lo/hi for this bucket
    int v = (t < B_BKT) ? bcnt[t] : 0;
    sc[t] = v;
    __syncthreads();
    for (int off = 1; off < 512; off <<= 1) {
        int u = (t >= off) ? sc[t - off] : 0;
        __syncthreads();
        sc[t] += u;
        __syncthreads();
    }
    if (t == b) { s_lo = sc[t] - v; s_hi = sc[t]; }
    __syncthreads();
    int lo = s_lo, hi = s_hi;
    int cnt = hi - lo;
    for (int i = t; i < NPB; i += 512) ldeg[i] = 0;
    __syncthreads();
    for (int i = t; i < cnt; i += 512) {
        int2 r = rb[lo + i];
        if (i < BKT_CAP) stage[i] = r;
        atomicAdd(&ldeg[((unsigned)r.x) >> 17], 1);
    }
    __syncthreads();
    int dv = ldeg[t];
    lscan[t] = dv;
    __syncthreads();
    for (int off = 1; off < 512; off <<= 1) {
        int u = (t >= off) ? lscan[t - off] : 0;
        __syncthreads();
        lscan[t] += u;
        __syncthreads();
    }
    int excl = lscan[t] - dv;
    int node = b * NPB + t;
    if (node < n_nodes) rowptr[node] = lo + excl;
    if (b == B_BKT - 1 && t == 0) rowptr[n_nodes] = N_EDGES;
    ldeg[t] = lo + excl;              // reuse as cursor
    __syncthreads();
    for (int i = t; i < cnt; i += 512) {
        int2 r = (i < BKT_CAP) ? stage[i] : rb[lo + i];
        int dl = ((unsigned)r.x) >> 17;
        int pos = atomicAdd(&ldeg[dl], 1);
        pe[pos] = make_int2(r.x & 0x1FFFF, r.y);
    }
}

// ---------------- propagation: per-node gather (no atomics) ----------------
// 12 lanes/node, float4 per lane, 8-edge unroll (R15 proven).
__global__ __launch_bounds__(192) void prop_kernel(const float* __restrict__ yin,
                                                   float* __restrict__ yout,
                                                   const int* __restrict__ rowptr,
                                                   const int2* __restrict__ pe,
                                                   const float* __restrict__ dfn,
                                                   int n_nodes) {
    int n = blockIdx.x * 16 + threadIdx.y;
    if (n >= n_nodes) return;
    int d4 = threadIdx.x * 4;  // 0,4,...,44
    int lo = rowptr[n];
    int hi = rowptr[n + 1];
    float4 acc = make_float4(0.f, 0.f, 0.f, 0.f);
    int e = lo;
    for (; e + 8 <= hi; e += 8) {
        int2 e0 = pe[e],     e1 = pe[e + 1], e2 = pe[e + 2], e3 = pe[e + 3];
        int2 e4 = pe[e + 4], e5 = pe[e + 5], e6 = pe[e + 6], e7 = pe[e + 7];
        float4 v0 = *(const float4*)&yin[(size_t)e0.x * DIM_IN + d4];
        float4 v1 = *(const float4*)&yin[(size_t)e1.x * DIM_IN + d4];
        float4 v2 = *(const float4*)&yin[(size_t)e2.x * DIM_IN + d4];
        float4 v3 = *(const float4*)&yin[(size_t)e3.x * DIM_IN + d4];
        float4 v4 = *(const float4*)&yin[(size_t)e4.x * DIM_IN + d4];
        float4 v5 = *(const float4*)&yin[(size_t)e5.x * DIM_IN + d4];
        float4 v6 = *(const float4*)&yin[(size_t)e6.x * DIM_IN + d4];
        float4 v7 = *(const float4*)&yin[(size_t)e7.x * DIM_IN + d4];
        float w0 = __int_as_float(e0.y), w1 = __int_as_float(e1.y);
        float w2 = __int_as_float(e2.y), w3 = __int_as_float(e3.y);
        float w4 = __int_as_float(e4.y), w5 = __int_as_float(e5.y);
        float w6 = __int_as_float(e6.y), w7 = __int_as_float(e7.y);
        acc.x = fmaf(v0.x, w0, acc.x); acc.y = fmaf(v0.y, w0, acc.y);
        acc.z = fmaf(v0.z, w0, acc.z); acc.w = fmaf(v0.w, w0, acc.w);
        acc.x = fmaf(v1.x, w1, acc.x); acc.y = fmaf(v1.y, w1, acc.y);
        acc.z = fmaf(v1.z, w1, acc.z); acc.w = fmaf(v1.w, w1, acc.w);
        acc.x = fmaf(v2.x, w2, acc.x); acc.y = fmaf(v2.y, w2, acc.y);
        acc.z = fmaf(v2.z, w2, acc.z); acc.w = fmaf(v2.w, w2, acc.w);
        acc.x = fmaf(v3.x, w3, acc.x); acc.y = fmaf(v3.y, w3, acc.y);
        acc.z = fmaf(v3.z, w3, acc.z); acc.w = fmaf(v3.w, w3, acc.w);
        acc.x = fmaf(v4.x, w4, acc.x); acc.y = fmaf(v4.y, w4, acc.y);
        acc.z = fmaf(v4.z, w4, acc.z); acc.w = fmaf(v4.w, w4, acc.w);
        acc.x = fmaf(v5.x, w5, acc.x); acc.y = fmaf(v5.y, w5, acc.y);
        acc.z = fmaf(v5.z, w5, acc.z); acc.w = fmaf(v5.w, w5, acc.w);
        acc.x = fmaf(v6.x, w6, acc.x); acc.y = fmaf(v6.y, w6, acc.y);
        acc.z = fmaf(v6.z, w6, acc.z); acc.w = fmaf(v6.w, w6, acc.w);
        acc.x = fmaf(v7.x, w7, acc.x); acc.y = fmaf(v7.y, w7, acc.y);
        acc.z = fmaf(v7.z, w7, acc.z); acc.w = fmaf(v7.w, w7, acc.w);
    }
    for (; e + 4 <= hi; e += 4) {
        int2 e0 = pe[e], e1 = pe[e + 1], e2 = pe[e + 2], e3 = pe[e + 3];
        float4 v0 = *(const float4*)&yin[(size_t)e0.x * DIM_IN + d4];
        float4 v1 = *(const float4*)&yin[(size_t)e1.x * DIM_IN + d4];
        float4 v2 = *(const float4*)&yin[(size_t)e2.x * DIM_IN + d4];
        float4 v3 = *(const float4*)&yin[(size_t)e3.x * DIM_IN + d4];
        float w0 = __int_as_float(e0.y), w1 = __int_as_float(e1.y);
        float w2 = __int_as_float(e2.y), w3 = __int_as_float(e3.y);
        acc.x = fmaf(v0.x, w0, acc.x); acc.y = fmaf(v0.y, w0, acc.y);
        acc.z = fmaf(v0.z, w0, acc.z); acc.w = fmaf(v0.w, w0, acc.w);
        acc.x = fmaf(v1.x, w1, acc.x); acc.y = fmaf(v1.y, w1, acc.y);
        acc.z = fmaf(v1.z, w1, acc.z); acc.w = fmaf(v1.w, w1, acc.w);
        acc.x = fmaf(v2.x, w2, acc.x); acc.y = fmaf(v2.y, w2, acc.y);
        acc.z = fmaf(v2.z, w2, acc.z); acc.w = fmaf(v2.w, w2, acc.w);
        acc.x = fmaf(v3.x, w3, acc.x); acc.y = fmaf(v3.y, w3, acc.y);
        acc.z = fmaf(v3.z, w3, acc.z); acc.w = fmaf(v3.w, w3, acc.w);
    }
    for (; e < hi; ++e) {
        int2 ee = pe[e];
        float w = __int_as_float(ee.y);
        float4 v = *(const float4*)&yin[(size_t)ee.x * DIM_IN + d4];
        acc.x = fmaf(v.x, w, acc.x); acc.y = fmaf(v.y, w, acc.y);
        acc.z = fmaf(v.z, w, acc.z); acc.w = fmaf(v.w, w, acc.w);
    }
    if (dfn) {
        float s = dfn[n];
        acc.x *= s; acc.y *= s; acc.z *= s; acc.w *= s;
    }
    *(float4*)&yout[(size_t)n * DIM_IN + d4] = acc;
}

// ---------------- fallback: atomic scatter (R6 proven path) ----------------
__global__ __launch_bounds__(192) void scatter1_kernel(
    const float* __restrict__ yin, float* __restrict__ yout,
    const int* __restrict__ sn, const int* __restrict__ en,
    const float* __restrict__ dfs, int E)
{
    int e = blockIdx.x * 4 + threadIdx.y;
    if (e >= E) return;
    int d = threadIdx.x;
    int s = sn[e], dn = en[e];
    float v = yin[(size_t)s * DIM_IN + d] * dfs[e];
    atomicAdd(&yout[(size_t)dn * DIM_IN + d], v);
}
__global__ __launch_bounds__(192) void scatter2_kernel(
    const float* __restrict__ yin, float* __restrict__ yout,
    const int* __restrict__ sn, const int* __restrict__ en,
    const float* __restrict__ dfs, const float* __restrict__ df, int E)
{
    int e = blockIdx.x * 4 + threadIdx.y;
    if (e >= E) return;
    int d = threadIdx.x;
    int s = sn[e], dn = en[e];
    float w = dfs[e] * df[s];
    float v = yin[(size_t)s * DIM_IN + d] * w;
    atomicAdd(&yout[(size_t)dn * DIM_IN + d], v);
}
__global__ __launch_bounds__(256) void zerof_kernel(float* __restrict__ p, int n) {
    int i = blockIdx.x * 256 + threadIdx.x;
    if (i < n) p[i] = 0.0f;
}

// ---------------- fused MLP (R10-exact body) + tail passthrough ----------------
// Blocks [0, MLPB): mlp. Blocks [MLPB, MLPB+TAILB): grid-strided tail.
// Tail's streaming traffic overlaps mlp's compute-bound blocks.
__global__ __launch_bounds__(256) void mlp_tail_kernel(
    const float* __restrict__ y2, const float* __restrict__ df,
    const float* __restrict__ W1, const float* __restrict__ b1,
    const float* __restrict__ W2, const float* __restrict__ b2,
    const int* __restrict__ sn, const int* __restrict__ en,
    const float* __restrict__ dfs,
    float* __restrict__ out, int n_nodes)
{
    __shared__ float xs[64 * DIM_IN];  // 12.3 KB
    __shared__ float hs[64 * DIM_U];   // 32.8 KB
    int t = threadIdx.x;

    if (blockIdx.x >= MLPB) {
        // ---- tail part ----
        const int E = N_EDGES, Nn = N_NODES;
        int total = 3 * E + Nn;
        for (int i = (blockIdx.x - MLPB) * 256 + t; i < total; i += TAILB * 256) {
            float v;
            if (i < E) v = (float)sn[i];
            else if (i < 2 * E) v = (float)en[i - E];
            else if (i < 3 * E) v = dfs[i - 2 * E];
            else v = df[i - 3 * E];
            __builtin_nontemporal_store(v, &out[(size_t)Nn * DIM_OUT + (size_t)i]);
        }
        return;
    }

    // ---- mlp part (R10-exact) ----
    int node0 = blockIdx.x * 64;

    for (int i4 = t; i4 < 64 * DIM_IN / 4; i4 += 256) {
        int n = node0 + i4 / (DIM_IN / 4);
        float4 v = make_float4(0.f, 0.f, 0.f, 0.f);
        if (n < n_nodes) {
            v = *(const float4*)&y2[(size_t)node0 * DIM_IN + (size_t)i4 * 4];
            float s = df[n];
            v.x *= s; v.y *= s; v.z *= s; v.w *= s;
        }
        *(float4*)&xs[i4 * 4] = v;
    }
    __syncthreads();

    int cg = t & 31;   // cols 4*cg..4*cg+3
    int ng = t >> 5;   // nodes 8*ng..8*ng+7

    float acc[8][4];
    #pragma unroll
    for (int m = 0; m < 8; ++m)
        #pragma unroll
        for (int c = 0; c < 4; ++c) acc[m][c] = 0.f;
    const float* xbase = &xs[ng * 8 * DIM_IN];
    for (int k = 0; k < DIM_IN; ++k) {
        float4 wv = *(const float4*)&W1[k * DIM_U + cg * 4];
        #pragma unroll
        for (int m = 0; m < 8; ++m) {
            float xv = xbase[m * DIM_IN + k];
            acc[m][0] = fmaf(xv, wv.x, acc[m][0]);
            acc[m][1] = fmaf(xv, wv.y, acc[m][1]);
            acc[m][2] = fmaf(xv, wv.z, acc[m][2]);
            acc[m][3] = fmaf(xv, wv.w, acc[m][3]);
        }
    }
    {
        float4 bb = *(const float4*)&b1[cg * 4];
        #pragma unroll
        for (int m = 0; m < 8; ++m) {
            float4 h;
            h.x = fmaxf(acc[m][0] + bb.x, 0.f);
            h.y = fmaxf(acc[m][1] + bb.y, 0.f);
            h.z = fmaxf(acc[m][2] + bb.z, 0.f);
            h.w = fmaxf(acc[m][3] + bb.w, 0.f);
            *(float4*)&hs[(ng * 8 + m) * DIM_U + cg * 4] = h;
        }
    }
    __syncthreads();

    float acc2[8][4];
    #pragma unroll
    for (int m = 0; m < 8; ++m)
        #pragma unroll
        for (int c = 0; c < 4; ++c) acc2[m][c] = 0.f;
    const float* hbase = &hs[ng * 8 * DIM_U];
    for (int k = 0; k < DIM_U; ++k) {
        float4 wv = *(const float4*)&W2[k * DIM_OUT + cg * 4];
        #pragma unroll
        for (int m = 0; m < 8; ++m) {
            float hv = hbase[m * DIM_U + k];
            acc2[m][0] = fmaf(hv, wv.x, acc2[m][0]);
            acc2[m][1] = fmaf(hv, wv.y, acc2[m][1]);
            acc2[m][2] = fmaf(hv, wv.z, acc2[m][2]);
            acc2[m][3] = fmaf(hv, wv.w, acc2[m][3]);
        }
    }
    {
        float4 bb = *(const float4*)&b2[cg * 4];
        #pragma unroll
        for (int m = 0; m < 8; ++m) {
            int n = node0 + ng * 8 + m;
            if (n < n_nodes) {
                float4 o;
                o.x = acc2[m][0] + bb.x;
                o.y = acc2[m][1] + bb.y;
                o.z = acc2[m][2] + bb.z;
                o.w = acc2[m][3] + bb.w;
                *(float4*)&out[(size_t)n * DIM_OUT + cg * 4] = o;
            }
        }
    }
}

extern "C" void kernel_launch(void* const* d_in, const int* in_sizes, int n_in,
                              void* d_out, int out_size, void* d_ws, size_t ws_size,
                              hipStream_t stream) {
    const float* y   = (const float*)d_in[0];
    const int* start = (const int*)d_in[1];
    const int* endn  = (const int*)d_in[2];
    const float* dfs = (const float*)d_in[3];
    const float* df  = (const float*)d_in[4];
    const float* W1  = (const float*)d_in[5];
    const float* b1  = (const float*)d_in[6];
    const float* W2  = (const float*)d_in[7];
    const float* b2  = (const float*)d_in[8];
    float* out = (float*)d_out;

    const int N = N_NODES, E = N_EDGES;
    const size_t Y_ELEMS = (size_t)N * DIM_IN;  // 4.8M floats

    // Workspace carve (CSR path): ~52 MB (rb aliases pe -> in-place CSR build)
    char* ws = (char*)d_ws;
    size_t off = 0;
    auto carve = [&](size_t bytes) -> void* {
        void* p = ws + off;
        off = (off + bytes + 255) & ~(size_t)255;
        return p;
    };
    int*   rowptr  = (int*)carve((size_t)(N + 1) * 4);
    int*   partial = (int*)carve((size_t)B_BKT * AP_WGS * 4);   // 200 KB
    int*   bcnt    = (int*)carve((size_t)B_BKT * 4);
    int2*  pedge   = (int2*)carve((size_t)E * 8);               // rb == pe (in place)
    float* y1      = (float*)carve(Y_ELEMS * 4);
    float* y2      = (float*)carve(Y_ELEMS * 4);
    size_t CSR_NEED = off;                                      // ~52 MB

    if (ws_size >= CSR_NEED) {
        // ---- deterministic bucket-binned CSR build (no contended atomics) ----
        histcount_kernel<<<AP_WGS, 256, 0, stream>>>(endn, partial);
        colscan_kernel<<<B_BKT, 256, 0, stream>>>(partial, bcnt);
        scatter_rb_kernel<<<AP_WGS, 256, 0, stream>>>(start, endn, dfs, partial,
                                                      bcnt, pedge);
        bucket_fill_kernel<<<B_BKT, 512, 0, stream>>>(pedge, bcnt, rowptr,
                                                      pedge, N);
        // Pass 1: y1 = gather-sum(y * w) * df[n]   (df folded into epilogue)
        prop_kernel<<<(N + 15) / 16, dim3(12, 16), 0, stream>>>(y, y1, rowptr, pedge,
                                                                df, N);
        // Pass 2: y2 = gather-sum(y1 * w)          (mlp applies final df)
        prop_kernel<<<(N + 15) / 16, dim3(12, 16), 0, stream>>>(y1, y2, rowptr, pedge,
                                                                nullptr, N);
    } else {
        // ---- fallback: R6 proven atomic-scatter path (needs 38.4 MB) ----
        float* fy1 = (float*)d_ws;
        float* fy2 = fy1 + Y_ELEMS;
        y2 = fy2;
        int zn = (int)(2 * Y_ELEMS);
        zerof_kernel<<<(zn + 255) / 256, 256, 0, stream>>>(fy1, zn);
        scatter1_kernel<<<(E + 3) / 4, dim3(48, 4), 0, stream>>>(y, fy1, start, endn,
                                                                 dfs, E);
        scatter2_kernel<<<(E + 3) / 4, dim3(48, 4), 0, stream>>>(fy1, fy2, start, endn,
                                                                 dfs, df, E);
    }

    // Fused: MLP on x = y2*df -> out[0..N*128)  +  tail passthrough
    mlp_tail_kernel<<<MLPB + TAILB, 256, 0, stream>>>(
        y2, df, W1, b1, W2, b2, start, endn, dfs, out, N);
}